// Round 14
// baseline (306.618 us; speedup 1.0000x reference)
//
#include <hip/hip_runtime.h>
#include <hip/hip_cooperative_groups.h>

namespace cg = cooperative_groups;

#define NROWS 8192
#define DDIM 256
#define BT 64
#define BK 64
#define GT (NROWS / BT)            // 128 tile-rows
#define NBT (GT * (GT + 1) / 2)    // 8256 upper-triangle tiles

using bf16x8 = __attribute__((ext_vector_type(8))) __bf16;
using f32x4  = __attribute__((ext_vector_type(4))) float;

__device__ __forceinline__ void glds16(const unsigned short* g, unsigned short* l) {
    // async global->LDS DMA, 16B/lane; LDS dest = wave-uniform base + lane*16
    __builtin_amdgcn_global_load_lds(
        (const __attribute__((address_space(1))) unsigned int*)g,
        (__attribute__((address_space(3))) unsigned int*)l,
        16, 0, 0);
}

__device__ __forceinline__ unsigned short f2bf(float f) {
    unsigned int b = __float_as_uint(f);
    unsigned int r = b + 0x7fffu + ((b >> 16) & 1u);
    return (unsigned short)(r >> 16);
}

// Single cooperative persistent kernel (round-14): phases
//   1) rowstats (grid-stride over row-quads)
//   2) grid.sync; upper-triangle E~.E~^T MFMA GEMM, grid-stride over tiles,
//      accumulators carried across tiles (one block-reduction total)
//   3) grid.sync; block 0 reduces per-block partials + rabs -> loss
// Rationale: GEMM is ~43us invariant across occupancy 35->62% (rounds
// 10/12/13) -> structural floor for this schedule; remaining measured
// target is ~25us of rowstats+finalize+launch gaps. Phase-2 body is
// byte-identical to round-13's block body.
// Co-residency: LDS 18.4KB (8 blocks/CU fit), __launch_bounds__(256,8)
// pins <=64 VGPR (measured live state 28, round-13).
__global__ __launch_bounds__(256, 8) void snr_fused_kernel(
    const float* __restrict__ x, const int* __restrict__ labels,
    unsigned short* __restrict__ ebf, float* __restrict__ aP,
    float* __restrict__ bsv, float* __restrict__ rabs,
    float* __restrict__ partials, float* __restrict__ out)
{
    __shared__ __align__(16) unsigned short As[BT * BK];   // 8 KB, swizzled chunks
    __shared__ __align__(16) unsigned short Bs[BT * BK];   // 8 KB
    __shared__ float sAPi[BT], sBsi[BT];
    __shared__ float sAPj[BT], sBsj[BT];
    __shared__ int   sLi[BT], sLj[BT];
    __shared__ float redbuf[4][5];

    int tid  = threadIdx.x;
    int lane = tid & 63;
    int wave = tid >> 6;

    // ---------------- phase 1: rowstats ----------------
    //   dist_ij = (b_i + b_j - (e~_i . e~_j)/128) / b_i
    //   v_neg(i,j) = fmaf(aP_i, raw + bs_j, -0.8),  v_pos = 0.19 - v_neg
    //   aP = (1/b)/128, bs = -128*b  (aP*bs = -1 exactly)
    for (int q = blockIdx.x; q < NROWS / 4; q += gridDim.x) {
        int row = q * 4 + wave;
        const float4 v = reinterpret_cast<const float4*>(x + (size_t)row * DDIM)[lane];
        float ss = v.x * v.x + v.y * v.y + v.z * v.z + v.w * v.w;
        float sm = v.x + v.y + v.z + v.w;
        #pragma unroll
        for (int off = 32; off >= 1; off >>= 1) {
            ss += __shfl_xor(ss, off);
            sm += __shfl_xor(sm, off);
        }
        float invn = 1.0f / sqrtf(ss);
        float m = sm * invn * (1.0f / DDIM);

        ushort4 o;
        o.x = f2bf(v.x * invn - m);
        o.y = f2bf(v.y * invn - m);
        o.z = f2bf(v.z * invn - m);
        o.w = f2bf(v.w * invn - m);
        reinterpret_cast<ushort4*>(ebf + (size_t)row * DDIM)[lane] = o;

        if (lane == 0) {
            float s  = ss * invn * invn * (1.0f / DDIM);
            float b  = s - m * m;
            float a  = 1.0f / b;
            aP[row]   = a * (1.0f / 128.0f);
            bsv[row]  = -128.0f * b;
            rabs[row] = fabsf(sm * invn);
        }
    }

    cg::this_grid().sync();

    // ---------------- phase 2: GEMM over tiles ----------------
    int wr = (wave >> 1) * 32;
    int wc = (wave & 1) * 32;
    int mrow = lane & 15;
    int kch  = lane >> 4;          // 16B k-chunk within half

    // tile-independent: fragment LDS offsets (swizzle-aware) + LDS dests
    int offA[2][2], offB[2][2];
    #pragma unroll
    for (int t4 = 0; t4 < 2; ++t4) {
        int rA = wr + t4 * 16 + mrow;
        int rB = wc + t4 * 16 + mrow;
        #pragma unroll
        for (int h = 0; h < 2; ++h) {
            offA[t4][h] = (rA * 8 + ((h * 4 + kch) ^ (rA & 7))) * 8;
            offB[t4][h] = (rB * 8 + ((h * 4 + kch) ^ (rB & 7))) * 8;
        }
    }
    unsigned short* lpA[2];
    unsigned short* lpB[2];
    int srow[2], skc[2];
    #pragma unroll
    for (int p = 0; p < 2; ++p) {
        int q = p * 256 + tid;
        srow[p] = q >> 3;
        skc[p]  = ((q & 7) ^ (srow[p] & 7)) * 8;
        lpA[p] = As + q * 8;
        lpB[p] = Bs + q * 8;
    }

    float Sn = 0.f, Sp = 0.f;
    unsigned Cn = 0u, Cp = 0u;   // wave-uniform (ballot/popc) -> SGPR accumulators
    int subr = (lane >> 4) * 4;
    int cj   = lane & 15;

    for (int t = blockIdx.x; t < NBT; t += gridDim.x) {
        // decode triangular tile id -> (bi, bj), bi <= bj
        int bi = (int)((2.0f * GT + 1.0f
                        - sqrtf((2.0f * GT + 1.0f) * (2.0f * GT + 1.0f) - 8.0f * (float)t)) * 0.5f);
        while ((bi + 1) * GT - ((bi + 1) * bi) / 2 <= t) ++bi;
        while (bi * GT - (bi * (bi - 1)) / 2 > t) --bi;
        int bj = bi + (t - (bi * GT - (bi * (bi - 1)) / 2));
        int rowBase = bi * BT, colBase = bj * BT;
        bool diag = (bi == bj);

        // stage per-row / per-col epilogue constants (covered by first K-loop barrier)
        if (tid < BT) {
            int gi = rowBase + tid;
            sAPi[tid] = aP[gi]; sBsi[tid] = bsv[gi];
            sLi[tid] = labels[gi];
        } else if (tid < 2 * BT) {
            int tt = tid - BT;
            int gj = colBase + tt;
            sAPj[tt] = aP[gj]; sBsj[tt] = bsv[gj];
            sLj[tt] = labels[gj];
        }

        const unsigned short* gA[2];
        const unsigned short* gB[2];
        #pragma unroll
        for (int p = 0; p < 2; ++p) {
            gA[p] = ebf + (size_t)(rowBase + srow[p]) * DDIM + skc[p];
            gB[p] = ebf + (size_t)(colBase + srow[p]) * DDIM + skc[p];
        }

        f32x4 acc[2][2];
        #pragma unroll
        for (int a = 0; a < 2; ++a)
            #pragma unroll
            for (int b = 0; b < 2; ++b)
                acc[a][b] = (f32x4){0.f, 0.f, 0.f, 0.f};

        for (int it = 0; it < 4; ++it) {
            #pragma unroll
            for (int p = 0; p < 2; ++p) {
                glds16(gA[p], lpA[p]);
                glds16(gB[p], lpB[p]);
                gA[p] += BK;
                gB[p] += BK;
            }
            asm volatile("s_waitcnt vmcnt(0)" ::: "memory");
            __syncthreads();

            #pragma unroll
            for (int h = 0; h < 2; ++h) {
                bf16x8 aF[2], bF[2];
                #pragma unroll
                for (int t4 = 0; t4 < 2; ++t4) {
                    aF[t4] = *reinterpret_cast<const bf16x8*>(As + offA[t4][h]);
                    bF[t4] = *reinterpret_cast<const bf16x8*>(Bs + offB[t4][h]);
                }
                #pragma unroll
                for (int ti = 0; ti < 2; ++ti)
                    #pragma unroll
                    for (int tj = 0; tj < 2; ++tj)
                        acc[ti][tj] = __builtin_amdgcn_mfma_f32_16x16x32_bf16(aF[ti], bF[tj], acc[ti][tj], 0, 0, 0);
            }
            __syncthreads();
        }

        // epilogue with wave-uniform rare-site skip (bit-exact: skipped
        // sites contribute exactly 0). ~88% of sites take the fast path.
        float aPC[2], bsC[2];
        int LCj[2];
        #pragma unroll
        for (int tj = 0; tj < 2; ++tj) {
            int lj = wc + tj * 16 + cj;
            aPC[tj] = sAPj[lj]; bsC[tj] = sBsj[lj];
            LCj[tj] = sLj[lj];
        }

        if (!diag) {
            #pragma unroll
            for (int ti = 0; ti < 2; ++ti) {
                #pragma unroll
                for (int r = 0; r < 4; ++r) {
                    int li = wr + ti * 16 + subr + r;
                    float aR = sAPi[li], bR = sBsi[li];
                    int LR = sLi[li];
                    #pragma unroll
                    for (int tj = 0; tj < 2; ++tj) {
                        float raw = acc[ti][tj][r];
                        float v1 = fmaf(aR, raw + bsC[tj], -0.8f);       // v_neg (i,j)
                        float v2 = fmaf(aPC[tj], raw + bR, -0.8f);       // v_neg (j,i)
                        bool same = (LR == LCj[tj]);
                        unsigned long long b1 = __ballot(v1 > 0.f);
                        unsigned long long b2 = __ballot(v2 > 0.f);
                        unsigned long long ms = __ballot(same);
                        if (b1 | b2 | ms) {
                            float nz = fmaxf(v1, 0.f) + fmaxf(v2, 0.f);
                            Sn += same ? 0.f : nz;
                            float pz = fmaxf(0.19f - v1, 0.f) + fmaxf(0.19f - v2, 0.f);
                            Sp += same ? pz : 0.f;
                            Cn += (unsigned)__popcll(b1 & ~ms)
                                + (unsigned)__popcll(b2 & ~ms);
                            Cp += (unsigned)__popcll(__ballot(v1 < 0.19f) & ms)
                                + (unsigned)__popcll(__ballot(v2 < 0.19f) & ms);
                        }
                    }
                }
            }
        } else {
            #pragma unroll
            for (int ti = 0; ti < 2; ++ti) {
                #pragma unroll
                for (int r = 0; r < 4; ++r) {
                    int li = wr + ti * 16 + subr + r;
                    float aR = sAPi[li];
                    int LR = sLi[li];
                    #pragma unroll
                    for (int tj = 0; tj < 2; ++tj) {
                        int lj = wc + tj * 16 + cj;
                        float raw = acc[ti][tj][r];
                        float v1 = fmaf(aR, raw + bsC[tj], -0.8f);
                        bool same = (LR == LCj[tj]);                 // includes self
                        bool pok  = same && (li != lj);              // eye excluded from pos
                        unsigned long long b1 = __ballot(v1 > 0.f);
                        unsigned long long ms = __ballot(same);
                        if (b1 | ms) {
                            unsigned long long mp = __ballot(pok);
                            Sn += same ? 0.f : fmaxf(v1, 0.f);
                            float pz = fmaxf(0.19f - v1, 0.f);
                            Sp += pok ? pz : 0.f;
                            Cn += (unsigned)__popcll(b1 & ~ms);
                            Cp += (unsigned)__popcll(__ballot(v1 < 0.19f) & mp);
                        }
                    }
                }
            }
        }
        __syncthreads();   // epilogue const-reads done before next tile restages
    }

    // once-per-block reduction of the carried accumulators
    #pragma unroll
    for (int off = 32; off >= 1; off >>= 1) {
        Sn += __shfl_down(Sn, off);
        Sp += __shfl_down(Sp, off);
    }
    if (lane == 0) {
        redbuf[wave][0] = Sn; redbuf[wave][1] = (float)Cn;
        redbuf[wave][2] = Sp; redbuf[wave][3] = (float)Cp;
    }
    __syncthreads();
    if (tid < 4) {
        partials[blockIdx.x * 4 + tid] =
            redbuf[0][tid] + redbuf[1][tid] + redbuf[2][tid] + redbuf[3][tid];
    }

    cg::this_grid().sync();

    // ---------------- phase 3: block 0 finalize ----------------
    if (blockIdx.x == 0) {
        float s0 = 0, s1 = 0, s2 = 0, s3 = 0, rr = 0;
        int g = gridDim.x;
        for (int i = tid; i < g; i += 256) {
            float4 p = reinterpret_cast<const float4*>(partials)[i];
            s0 += p.x; s1 += p.y; s2 += p.z; s3 += p.w;
        }
        for (int i = tid; i < NROWS; i += 256) rr += rabs[i];

        #pragma unroll
        for (int off = 32; off >= 1; off >>= 1) {
            s0 += __shfl_down(s0, off);
            s1 += __shfl_down(s1, off);
            s2 += __shfl_down(s2, off);
            s3 += __shfl_down(s3, off);
            rr += __shfl_down(rr, off);
        }
        __syncthreads();   // redbuf reuse safe
        if (lane == 0) {
            redbuf[wave][0] = s0; redbuf[wave][1] = s1; redbuf[wave][2] = s2;
            redbuf[wave][3] = s3; redbuf[wave][4] = rr;
        }
        __syncthreads();
        if (tid == 0) {
            float a0 = 0, a1 = 0, a2 = 0, a3 = 0, a4 = 0;
            #pragma unroll
            for (int w = 0; w < 4; ++w) {
                a0 += redbuf[w][0]; a1 += redbuf[w][1]; a2 += redbuf[w][2];
                a3 += redbuf[w][3]; a4 += redbuf[w][4];
            }
            // guard: count==0 -> true masked sum is 0 -> reference yields 0
            float neg = (a1 > 0.5f) ? a0 / (a1 + 1e-12f) : 0.0f;
            float pos = (a3 > 0.5f) ? a2 / (a3 + 1e-12f) : 0.0f;
            out[0] = pos + neg + a4 * (0.1f / (float)NROWS);
        }
    }
}

extern "C" void kernel_launch(void* const* d_in, const int* in_sizes, int n_in,
                              void* d_out, int out_size, void* d_ws, size_t ws_size,
                              hipStream_t stream) {
    const float* embeds = (const float*)d_in[0];
    const int*   labels = (const int*)d_in[1];
    float* out = (float*)d_out;

    char* ws = (char*)d_ws;
    unsigned short* ebf = (unsigned short*)ws;              // 4 MB
    float* aP   = (float*)(ws + (size_t)NROWS * DDIM * 2);
    float* bsv  = aP + NROWS;
    float* rabs = bsv + NROWS;
    float* partials = rabs + NROWS;                         // grid*4 floats

    // co-resident grid size: blocks/CU (queried, clamp [1,8]) x 256 CUs
    static int gblocks = 0;
    if (gblocks == 0) {
        int per = 0;
        if (hipOccupancyMaxActiveBlocksPerMultiprocessor(&per, snr_fused_kernel, 256, 0)
                != hipSuccess || per < 1) per = 8;
        if (per > 8) per = 8;
        gblocks = per * 256;
        if (gblocks > NROWS / 4) gblocks = NROWS / 4;       // 2048 cap
    }

    void* args[] = {
        (void*)&embeds, (void*)&labels, (void*)&ebf, (void*)&aP,
        (void*)&bsv, (void*)&rabs, (void*)&partials, (void*)&out
    };
    hipLaunchCooperativeKernel((void*)snr_fused_kernel, dim3(gblocks), dim3(256),
                               args, 0, stream);
}

// Round 15
// 115.930 us; speedup vs baseline: 2.6449x; 2.6449x over previous
//
#include <hip/hip_runtime.h>

#define NROWS 8192
#define DDIM 256
#define BT 64
#define BK 64
#define GT (NROWS / BT)            // 128 tile-rows
#define NBT (GT * (GT + 1) / 2)    // 8256 upper-triangle blocks

using bf16x8 = __attribute__((ext_vector_type(8))) __bf16;
using f32x4  = __attribute__((ext_vector_type(4))) float;

__device__ __forceinline__ void glds16(const unsigned short* g, unsigned short* l) {
    // async global->LDS DMA, 16B/lane; LDS dest = wave-uniform base + lane*16
    __builtin_amdgcn_global_load_lds(
        (const __attribute__((address_space(1))) unsigned int*)g,
        (__attribute__((address_space(3))) unsigned int*)l,
        16, 0, 0);
}

__device__ __forceinline__ unsigned short f2bf(float f) {
    unsigned int b = __float_as_uint(f);
    unsigned int r = b + 0x7fffu + ((b >> 16) & 1u);
    return (unsigned short)(r >> 16);
}

// Kernel 1: one wave per row. Normalize, CENTER (e - mean), emit bf16 e~,
// and per-row epilogue constants:
//   dist_ij = (b_i + b_j - (e~_i . e~_j)/128) / b_i
//   v_neg(i,j) = 0.2 - dist_ij = fmaf(aP_i, raw + bs_j, -0.8),  raw = MFMA acc
//   v_pos(i,j) = dist_ij - 0.01 = 0.19 - v_neg(i,j)
//   with aP = (1/b)/128, bs = -128*b  (aP*bs = -1 exactly -> constant -0.8)
__global__ __launch_bounds__(256) void rowstats_kernel(
    const float* __restrict__ x, unsigned short* __restrict__ ebf,
    float* __restrict__ aP, float* __restrict__ bs,
    float* __restrict__ rabs)
{
    int wave = threadIdx.x >> 6;
    int lane = threadIdx.x & 63;
    int row  = blockIdx.x * 4 + wave;

    const float4 v = reinterpret_cast<const float4*>(x + (size_t)row * DDIM)[lane];
    float ss = v.x * v.x + v.y * v.y + v.z * v.z + v.w * v.w;
    float sm = v.x + v.y + v.z + v.w;
    #pragma unroll
    for (int off = 32; off >= 1; off >>= 1) {
        ss += __shfl_xor(ss, off);
        sm += __shfl_xor(sm, off);
    }
    float invn = 1.0f / sqrtf(ss);
    float m = sm * invn * (1.0f / DDIM);

    ushort4 o;
    o.x = f2bf(v.x * invn - m);
    o.y = f2bf(v.y * invn - m);
    o.z = f2bf(v.z * invn - m);
    o.w = f2bf(v.w * invn - m);
    reinterpret_cast<ushort4*>(ebf + (size_t)row * DDIM)[lane] = o;

    if (lane == 0) {
        float s  = ss * invn * invn * (1.0f / DDIM);
        float b  = s - m * m;
        float a  = 1.0f / b;
        aP[row]   = a * (1.0f / 128.0f);
        bs[row]   = -128.0f * b;
        rabs[row] = fabsf(sm * invn);
    }
}

// Kernel 2: upper-triangle E~.E~^T bf16 MFMA GEMM, 64x64 tiles, BK=64,
// DOUBLE-BUFFERED with COUNTED vmcnt (catalog T4):
//   issue next-tile glds -> s_waitcnt vmcnt(4) (cur done, next IN FLIGHT
//   across the barrier) -> raw s_barrier -> MFMA(cur) -> raw s_barrier.
// Round-10/13's single-buffer drained vmcnt(0) 4x/tile — the one stall
// extra waves can't hide (GEMM 43us invariant across occupancy 35->62%).
// Round-11's dbuf test kept vmcnt(0)+__syncthreads (no pipelining) — this
// is the first true counted-vmcnt variant. Raw barriers via inline asm
// ("memory" clobber stops the compiler hoisting next glds above them);
// ds_read->MFMA lgkm waits are compiler-inserted, so all reads of cur are
// retired before the trailing barrier (safe to overwrite next iter).
// Epilogue: round-13 verbatim (branchless + wave-uniform rare-site skip).
__global__ __launch_bounds__(256, 8) void snr_gemm_kernel(
    const unsigned short* __restrict__ ebf,
    const float* __restrict__ aP, const float* __restrict__ bs,
    const int* __restrict__ labels,
    float* __restrict__ partials)
{
    __shared__ __align__(16) unsigned short As[2][BT * BK];   // 2 x 8 KB
    __shared__ __align__(16) unsigned short Bs[2][BT * BK];   // 2 x 8 KB
    __shared__ float sAPi[BT], sBsi[BT];
    __shared__ float sAPj[BT], sBsj[BT];
    __shared__ int   sLi[BT], sLj[BT];
    __shared__ float redbuf[4][4];

    int tid  = threadIdx.x;
    int lane = tid & 63;
    int wave = tid >> 6;
    int wr = (wave >> 1) * 32;
    int wc = (wave & 1) * 32;

    // decode triangular block id -> (bi, bj), bi <= bj
    int t = blockIdx.x;
    int bi = (int)((2.0f * GT + 1.0f
                    - sqrtf((2.0f * GT + 1.0f) * (2.0f * GT + 1.0f) - 8.0f * (float)t)) * 0.5f);
    while ((bi + 1) * GT - ((bi + 1) * bi) / 2 <= t) ++bi;
    while (bi * GT - (bi * (bi - 1)) / 2 > t) --bi;
    int bj = bi + (t - (bi * GT - (bi * (bi - 1)) / 2));
    int rowBase = bi * BT, colBase = bj * BT;
    bool diag = (bi == bj);

    // stage per-row / per-col epilogue constants (visible by first barrier)
    if (tid < BT) {
        int gi = rowBase + tid;
        sAPi[tid] = aP[gi]; sBsi[tid] = bs[gi];
        sLi[tid] = labels[gi];
    } else if (tid < 2 * BT) {
        int tt = tid - BT;
        int gj = colBase + tt;
        sAPj[tt] = aP[gj]; sBsj[tt] = bs[gj];
        sLj[tt] = labels[gj];
    }

    // staging: 512 chunks/matrix; chunk q = p*256+tid; (row=q>>3, slot=q&7),
    // slot holds k-chunk kc = slot ^ (row&7)  (XOR swizzle, conflict-free)
    const unsigned short* gA[2];
    const unsigned short* gB[2];
    int qoff[2];
    #pragma unroll
    for (int p = 0; p < 2; ++p) {
        int q   = p * 256 + tid;
        int row = q >> 3;
        int kc  = (q & 7) ^ (row & 7);
        gA[p] = ebf + (size_t)(rowBase + row) * DDIM + kc * 8;
        gB[p] = ebf + (size_t)(colBase + row) * DDIM + kc * 8;
        qoff[p] = q * 8;
    }

    // fragment LDS offsets (elems), swizzle-aware
    int mrow = lane & 15;
    int kch  = lane >> 4;          // 16B k-chunk within half
    int offA[2][2], offB[2][2];
    #pragma unroll
    for (int t4 = 0; t4 < 2; ++t4) {
        int rA = wr + t4 * 16 + mrow;
        int rB = wc + t4 * 16 + mrow;
        #pragma unroll
        for (int h = 0; h < 2; ++h) {
            offA[t4][h] = (rA * 8 + ((h * 4 + kch) ^ (rA & 7))) * 8;
            offB[t4][h] = (rB * 8 + ((h * 4 + kch) ^ (rB & 7))) * 8;
        }
    }

    f32x4 acc[2][2];
    #pragma unroll
    for (int a = 0; a < 2; ++a)
        #pragma unroll
        for (int b = 0; b < 2; ++b)
            acc[a][b] = (f32x4){0.f, 0.f, 0.f, 0.f};

    // prologue: stage K-step 0 into buffer 0 (4 vmem insts/wave in flight)
    #pragma unroll
    for (int p = 0; p < 2; ++p) {
        glds16(gA[p], &As[0][qoff[p]]);
        glds16(gB[p], &Bs[0][qoff[p]]);
        gA[p] += BK;
        gB[p] += BK;
    }
    asm volatile("s_waitcnt lgkmcnt(0)" ::: "memory");   // consts ds_writes retired

    #pragma unroll
    for (int it = 0; it < 4; ++it) {
        int cur = it & 1;
        if (it < 3) {
            // issue next K-step into the other buffer; stays in flight
            #pragma unroll
            for (int p = 0; p < 2; ++p) {
                glds16(gA[p], &As[cur ^ 1][qoff[p]]);
                glds16(gB[p], &Bs[cur ^ 1][qoff[p]]);
                gA[p] += BK;
                gB[p] += BK;
            }
            asm volatile("s_waitcnt vmcnt(4)" ::: "memory");   // cur's 4 done, next's 4 in flight
        } else {
            asm volatile("s_waitcnt vmcnt(0)" ::: "memory");   // final drain
        }
        asm volatile("s_barrier" ::: "memory");                // cur staged for all waves

        #pragma unroll
        for (int h = 0; h < 2; ++h) {
            bf16x8 aF[2], bF[2];
            #pragma unroll
            for (int t4 = 0; t4 < 2; ++t4) {
                aF[t4] = *reinterpret_cast<const bf16x8*>(&As[cur][0] + offA[t4][h]);
                bF[t4] = *reinterpret_cast<const bf16x8*>(&Bs[cur][0] + offB[t4][h]);
            }
            #pragma unroll
            for (int ti = 0; ti < 2; ++ti)
                #pragma unroll
                for (int tj = 0; tj < 2; ++tj)
                    acc[ti][tj] = __builtin_amdgcn_mfma_f32_16x16x32_bf16(aF[ti], bF[tj], acc[ti][tj], 0, 0, 0);
        }
        if (it < 3)
            asm volatile("s_barrier" ::: "memory");            // reads of cur retired before overwrite
    }

    // ---------------- epilogue with wave-uniform rare-site skip ----------------
    int subr = (lane >> 4) * 4;
    int cj   = lane & 15;

    float aPC[2], bsC[2];
    int LCj[2];
    #pragma unroll
    for (int tj = 0; tj < 2; ++tj) {
        int lj = wc + tj * 16 + cj;
        aPC[tj] = sAPj[lj]; bsC[tj] = sBsj[lj];
        LCj[tj] = sLj[lj];
    }

    float Sn = 0.f, Sp = 0.f;
    unsigned Cn = 0u, Cp = 0u;   // wave-uniform (ballot/popc) -> SGPR accumulators

    if (!diag) {
        #pragma unroll
        for (int ti = 0; ti < 2; ++ti) {
            #pragma unroll
            for (int r = 0; r < 4; ++r) {
                int li = wr + ti * 16 + subr + r;
                float aR = sAPi[li], bR = sBsi[li];
                int LR = sLi[li];
                #pragma unroll
                for (int tj = 0; tj < 2; ++tj) {
                    float raw = acc[ti][tj][r];
                    float v1 = fmaf(aR, raw + bsC[tj], -0.8f);       // v_neg (i,j)
                    float v2 = fmaf(aPC[tj], raw + bR, -0.8f);       // v_neg (j,i)
                    bool same = (LR == LCj[tj]);
                    unsigned long long b1 = __ballot(v1 > 0.f);
                    unsigned long long b2 = __ballot(v2 > 0.f);
                    unsigned long long ms = __ballot(same);
                    if (b1 | b2 | ms) {                              // rare (~12% of sites)
                        float nz = fmaxf(v1, 0.f) + fmaxf(v2, 0.f);
                        Sn += same ? 0.f : nz;
                        float pz = fmaxf(0.19f - v1, 0.f) + fmaxf(0.19f - v2, 0.f);
                        Sp += same ? pz : 0.f;
                        Cn += (unsigned)__popcll(b1 & ~ms)
                            + (unsigned)__popcll(b2 & ~ms);
                        Cp += (unsigned)__popcll(__ballot(v1 < 0.19f) & ms)
                            + (unsigned)__popcll(__ballot(v2 < 0.19f) & ms);
                    }
                }
            }
        }
    } else {
        #pragma unroll
        for (int ti = 0; ti < 2; ++ti) {
            #pragma unroll
            for (int r = 0; r < 4; ++r) {
                int li = wr + ti * 16 + subr + r;
                float aR = sAPi[li];
                int LR = sLi[li];
                #pragma unroll
                for (int tj = 0; tj < 2; ++tj) {
                    int lj = wc + tj * 16 + cj;
                    float raw = acc[ti][tj][r];
                    float v1 = fmaf(aR, raw + bsC[tj], -0.8f);
                    bool same = (LR == LCj[tj]);                 // includes self
                    bool pok  = same && (li != lj);              // eye excluded from pos
                    unsigned long long b1 = __ballot(v1 > 0.f);
                    unsigned long long ms = __ballot(same);
                    if (b1 | ms) {
                        unsigned long long mp = __ballot(pok);
                        Sn += same ? 0.f : fmaxf(v1, 0.f);
                        float pz = fmaxf(0.19f - v1, 0.f);
                        Sp += pok ? pz : 0.f;
                        Cn += (unsigned)__popcll(b1 & ~ms);
                        Cp += (unsigned)__popcll(__ballot(v1 < 0.19f) & mp);
                    }
                }
            }
        }
    }

    // block reduction: Sn/Sp via shuffles; Cn/Cp already wave-uniform
    #pragma unroll
    for (int off = 32; off >= 1; off >>= 1) {
        Sn += __shfl_down(Sn, off);
        Sp += __shfl_down(Sp, off);
    }
    if (lane == 0) {
        redbuf[wave][0] = Sn; redbuf[wave][1] = (float)Cn;
        redbuf[wave][2] = Sp; redbuf[wave][3] = (float)Cp;
    }
    __syncthreads();
    if (tid < 4) {
        partials[blockIdx.x * 4 + tid] =
            redbuf[0][tid] + redbuf[1][tid] + redbuf[2][tid] + redbuf[3][tid];
    }
}

// Kernel 3: reduce per-block partials + per-row reg terms, emit scalar loss.
// Guard: if a count sums to exactly 0, the true masked sum is 0 too
// (reference yields 0/1e-12 = 0) -> emit 0 instead of residual/1e-12.
__global__ __launch_bounds__(256) void finalize_kernel(
    const float* __restrict__ partials, const float* __restrict__ rabs,
    float* __restrict__ out)
{
    int tid = threadIdx.x;
    float s0 = 0, s1 = 0, s2 = 0, s3 = 0, rr = 0;
    for (int i = tid; i < NBT; i += 256) {
        float4 p = reinterpret_cast<const float4*>(partials)[i];
        s0 += p.x; s1 += p.y; s2 += p.z; s3 += p.w;
    }
    for (int i = tid; i < NROWS; i += 256) rr += rabs[i];

    #pragma unroll
    for (int off = 32; off >= 1; off >>= 1) {
        s0 += __shfl_down(s0, off);
        s1 += __shfl_down(s1, off);
        s2 += __shfl_down(s2, off);
        s3 += __shfl_down(s3, off);
        rr += __shfl_down(rr, off);
    }
    __shared__ float red[4][5];
    int wave = tid >> 6, lane = tid & 63;
    if (lane == 0) {
        red[wave][0] = s0; red[wave][1] = s1; red[wave][2] = s2;
        red[wave][3] = s3; red[wave][4] = rr;
    }
    __syncthreads();
    if (tid == 0) {
        float a0 = 0, a1 = 0, a2 = 0, a3 = 0, a4 = 0;
        #pragma unroll
        for (int w = 0; w < 4; ++w) {
            a0 += red[w][0]; a1 += red[w][1]; a2 += red[w][2];
            a3 += red[w][3]; a4 += red[w][4];
        }
        float neg = (a1 > 0.5f) ? a0 / (a1 + 1e-12f) : 0.0f;
        float pos = (a3 > 0.5f) ? a2 / (a3 + 1e-12f) : 0.0f;
        out[0] = pos + neg + a4 * (0.1f / (float)NROWS);
    }
}

extern "C" void kernel_launch(void* const* d_in, const int* in_sizes, int n_in,
                              void* d_out, int out_size, void* d_ws, size_t ws_size,
                              hipStream_t stream) {
    const float* embeds = (const float*)d_in[0];
    const int*   labels = (const int*)d_in[1];
    float* out = (float*)d_out;

    char* ws = (char*)d_ws;
    unsigned short* ebf = (unsigned short*)ws;              // 4 MB
    float* aP   = (float*)(ws + (size_t)NROWS * DDIM * 2);
    float* bs   = aP + NROWS;
    float* rabs = bs + NROWS;
    float* partials = rabs + NROWS;                         // NBT*4 floats

    rowstats_kernel<<<NROWS / 4, 256, 0, stream>>>(embeds, ebf, aP, bs, rabs);

    snr_gemm_kernel<<<NBT, 256, 0, stream>>>(ebf, aP, bs, labels, partials);

    finalize_kernel<<<1, 256, 0, stream>>>(partials, rabs, out);
}

// Round 16
// 101.176 us; speedup vs baseline: 3.0305x; 1.1458x over previous
//
#include <hip/hip_runtime.h>

#define NROWS 8192
#define DDIM 256
#define BT 128
#define BK 64
#define GT (NROWS / BT)            // 64 tile-rows
#define NBT (GT * (GT + 1) / 2)    // 2080 upper-triangle blocks

using bf16x8 = __attribute__((ext_vector_type(8))) __bf16;
using f32x4  = __attribute__((ext_vector_type(4))) float;

__device__ __forceinline__ void glds16(const unsigned short* g, unsigned short* l) {
    // async global->LDS DMA, 16B/lane; LDS dest = wave-uniform base + lane*16
    __builtin_amdgcn_global_load_lds(
        (const __attribute__((address_space(1))) unsigned int*)g,
        (__attribute__((address_space(3))) unsigned int*)l,
        16, 0, 0);
}

__device__ __forceinline__ unsigned short f2bf(float f) {
    unsigned int b = __float_as_uint(f);
    unsigned int r = b + 0x7fffu + ((b >> 16) & 1u);
    return (unsigned short)(r >> 16);
}

// Kernel 1: one wave per row. Normalize, CENTER (e - mean), emit bf16 e~,
// and per-row epilogue constants:
//   dist_ij = (b_i + b_j - (e~_i . e~_j)/128) / b_i
//   v_neg(i,j) = 0.2 - dist_ij = fmaf(aP_i, raw + bs_j, -0.8),  raw = MFMA acc
//   v_pos(i,j) = dist_ij - 0.01 = 0.19 - v_neg(i,j)
//   with aP = (1/b)/128, bs = -128*b  (aP*bs = -1 exactly -> constant -0.8)
__global__ __launch_bounds__(256) void rowstats_kernel(
    const float* __restrict__ x, unsigned short* __restrict__ ebf,
    float* __restrict__ aP, float* __restrict__ bs,
    float* __restrict__ rabs)
{
    int wave = threadIdx.x >> 6;
    int lane = threadIdx.x & 63;
    int row  = blockIdx.x * 4 + wave;

    const float4 v = reinterpret_cast<const float4*>(x + (size_t)row * DDIM)[lane];
    float ss = v.x * v.x + v.y * v.y + v.z * v.z + v.w * v.w;
    float sm = v.x + v.y + v.z + v.w;
    #pragma unroll
    for (int off = 32; off >= 1; off >>= 1) {
        ss += __shfl_xor(ss, off);
        sm += __shfl_xor(sm, off);
    }
    float invn = 1.0f / sqrtf(ss);
    float m = sm * invn * (1.0f / DDIM);

    ushort4 o;
    o.x = f2bf(v.x * invn - m);
    o.y = f2bf(v.y * invn - m);
    o.z = f2bf(v.z * invn - m);
    o.w = f2bf(v.w * invn - m);
    reinterpret_cast<ushort4*>(ebf + (size_t)row * DDIM)[lane] = o;

    if (lane == 0) {
        float s  = ss * invn * invn * (1.0f / DDIM);
        float b  = s - m * m;
        float a  = 1.0f / b;
        aP[row]   = a * (1.0f / 128.0f);
        bs[row]   = -128.0f * b;
        rabs[row] = fabsf(sm * invn);
    }
}

// Kernel 2: upper-triangle E~.E~^T bf16 MFMA GEMM, 128x128 tiles, BK=64.
// TRAFFIC THEORY (round-16): at BT=64 the 8256x64KB = 528 MB of L2/L3
// staging ran at 528MB/43us = 12.3 TB/s — a cache-BW ceiling explaining
// why 6 schedule variants were all 43+-1us. BT=128 halves traffic to
// 266 MB (floor ~22us at the same BW). Round-8's 128-tile body (verified,
// VGPR 100) + round-13's skip-epilogue (the fat unconditional epilogue
// was why round-8 cost 53us). Plain launch_bounds (no pin — round-4).
__global__ __launch_bounds__(256) void snr_gemm_kernel(
    const unsigned short* __restrict__ ebf,
    const float* __restrict__ aP, const float* __restrict__ bs,
    const int* __restrict__ labels,
    float* __restrict__ partials)
{
    __shared__ __align__(16) unsigned short As[BT * BK];   // 16 KB, swizzled chunks
    __shared__ __align__(16) unsigned short Bs[BT * BK];   // 16 KB
    __shared__ float sAPi[BT], sBsi[BT];
    __shared__ float sAPj[BT], sBsj[BT];
    __shared__ int   sLi[BT], sLj[BT];
    __shared__ float redbuf[4][4];

    int tid  = threadIdx.x;
    int lane = tid & 63;
    int wave = tid >> 6;
    int wr = (wave >> 1) * 64;
    int wc = (wave & 1) * 64;

    // decode triangular block id -> (bi, bj), bi <= bj
    int t = blockIdx.x;
    int bi = (int)((2.0f * GT + 1.0f
                    - sqrtf((2.0f * GT + 1.0f) * (2.0f * GT + 1.0f) - 8.0f * (float)t)) * 0.5f);
    while ((bi + 1) * GT - ((bi + 1) * bi) / 2 <= t) ++bi;
    while (bi * GT - (bi * (bi - 1)) / 2 > t) --bi;
    int bj = bi + (t - (bi * GT - (bi * (bi - 1)) / 2));
    int rowBase = bi * BT, colBase = bj * BT;
    bool diag = (bi == bj);

    // stage per-row / per-col epilogue constants (covered by first K-loop barrier)
    if (tid < BT) {
        int gi = rowBase + tid;
        sAPi[tid] = aP[gi]; sBsi[tid] = bs[gi];
        sLi[tid] = labels[gi];
    } else {
        int tt = tid - BT;
        int gj = colBase + tt;
        sAPj[tt] = aP[gj]; sBsj[tt] = bs[gj];
        sLj[tt] = labels[gj];
    }

    // staging addresses: chunk q = p*256+tid; logical (row=q>>3, slot=q&7),
    // slot holds k-chunk kc = slot ^ (row&7)  (XOR swizzle, conflict-free)
    const unsigned short* gA[4];
    const unsigned short* gB[4];
    unsigned short* lpA[4];
    unsigned short* lpB[4];
    #pragma unroll
    for (int p = 0; p < 4; ++p) {
        int q   = p * 256 + tid;
        int row = q >> 3;
        int kc  = (q & 7) ^ (row & 7);
        gA[p] = ebf + (size_t)(rowBase + row) * DDIM + kc * 8;
        gB[p] = ebf + (size_t)(colBase + row) * DDIM + kc * 8;
        lpA[p] = As + q * 8;
        lpB[p] = Bs + q * 8;
    }

    // fragment LDS offsets (elems), swizzle-aware
    int mrow = lane & 15;
    int kch  = lane >> 4;          // 16B k-chunk within half
    int offA[4][2], offB[4][2];
    #pragma unroll
    for (int t4 = 0; t4 < 4; ++t4) {
        int rA = wr + t4 * 16 + mrow;
        int rB = wc + t4 * 16 + mrow;
        #pragma unroll
        for (int h = 0; h < 2; ++h) {
            offA[t4][h] = (rA * 8 + ((h * 4 + kch) ^ (rA & 7))) * 8;
            offB[t4][h] = (rB * 8 + ((h * 4 + kch) ^ (rB & 7))) * 8;
        }
    }

    f32x4 acc[4][4];
    #pragma unroll
    for (int a = 0; a < 4; ++a)
        #pragma unroll
        for (int b = 0; b < 4; ++b)
            acc[a][b] = (f32x4){0.f, 0.f, 0.f, 0.f};

    for (int it = 0; it < 4; ++it) {
        #pragma unroll
        for (int p = 0; p < 4; ++p) {
            glds16(gA[p], lpA[p]);
            glds16(gB[p], lpB[p]);
            gA[p] += BK;
            gB[p] += BK;
        }
        asm volatile("s_waitcnt vmcnt(0)" ::: "memory");
        __syncthreads();

        #pragma unroll
        for (int h = 0; h < 2; ++h) {
            bf16x8 aF[4], bF[4];
            #pragma unroll
            for (int t4 = 0; t4 < 4; ++t4) {
                aF[t4] = *reinterpret_cast<const bf16x8*>(As + offA[t4][h]);
                bF[t4] = *reinterpret_cast<const bf16x8*>(Bs + offB[t4][h]);
            }
            #pragma unroll
            for (int ti = 0; ti < 4; ++ti)
                #pragma unroll
                for (int tj = 0; tj < 4; ++tj)
                    acc[ti][tj] = __builtin_amdgcn_mfma_f32_16x16x32_bf16(aF[ti], bF[tj], acc[ti][tj], 0, 0, 0);
        }
        __syncthreads();
    }

    // ---------------- epilogue with wave-uniform rare-site skip ----------------
    // fast path = 2 fma + 3 ballots per site; guarded work only when some lane
    // has a firing neg hinge or a same-label pair (bit-exact: skipped sites
    // contribute exactly 0 to every accumulator).
    int subr = (lane >> 4) * 4;
    int cj   = lane & 15;

    float aPC[4], bsC[4];
    int LCj[4];
    #pragma unroll
    for (int tj = 0; tj < 4; ++tj) {
        int lj = wc + tj * 16 + cj;
        aPC[tj] = sAPj[lj]; bsC[tj] = sBsj[lj];
        LCj[tj] = sLj[lj];
    }

    float Sn = 0.f, Sp = 0.f;
    unsigned Cn = 0u, Cp = 0u;   // wave-uniform (ballot/popc) -> SGPR accumulators

    if (!diag) {
        #pragma unroll
        for (int ti = 0; ti < 4; ++ti) {
            #pragma unroll
            for (int r = 0; r < 4; ++r) {
                int li = wr + ti * 16 + subr + r;
                float aR = sAPi[li], bR = sBsi[li];
                int LR = sLi[li];
                #pragma unroll
                for (int tj = 0; tj < 4; ++tj) {
                    float raw = acc[ti][tj][r];
                    float v1 = fmaf(aR, raw + bsC[tj], -0.8f);       // v_neg (i,j)
                    float v2 = fmaf(aPC[tj], raw + bR, -0.8f);       // v_neg (j,i)
                    bool same = (LR == LCj[tj]);
                    unsigned long long b1 = __ballot(v1 > 0.f);
                    unsigned long long b2 = __ballot(v2 > 0.f);
                    unsigned long long ms = __ballot(same);
                    if (b1 | b2 | ms) {                              // rare (~12% of sites)
                        float nz = fmaxf(v1, 0.f) + fmaxf(v2, 0.f);
                        Sn += same ? 0.f : nz;
                        float pz = fmaxf(0.19f - v1, 0.f) + fmaxf(0.19f - v2, 0.f);
                        Sp += same ? pz : 0.f;
                        Cn += (unsigned)__popcll(b1 & ~ms)
                            + (unsigned)__popcll(b2 & ~ms);
                        Cp += (unsigned)__popcll(__ballot(v1 < 0.19f) & ms)
                            + (unsigned)__popcll(__ballot(v2 < 0.19f) & ms);
                    }
                }
            }
        }
    } else {
        #pragma unroll
        for (int ti = 0; ti < 4; ++ti) {
            #pragma unroll
            for (int r = 0; r < 4; ++r) {
                int li = wr + ti * 16 + subr + r;
                float aR = sAPi[li];
                int LR = sLi[li];
                #pragma unroll
                for (int tj = 0; tj < 4; ++tj) {
                    int lj = wc + tj * 16 + cj;
                    float raw = acc[ti][tj][r];
                    float v1 = fmaf(aR, raw + bsC[tj], -0.8f);
                    bool same = (LR == LCj[tj]);                 // includes self
                    bool pok  = same && (li != lj);              // eye excluded from pos
                    unsigned long long b1 = __ballot(v1 > 0.f);
                    unsigned long long ms = __ballot(same);
                    if (b1 | ms) {
                        unsigned long long mp = __ballot(pok);
                        Sn += same ? 0.f : fmaxf(v1, 0.f);
                        float pz = fmaxf(0.19f - v1, 0.f);
                        Sp += pok ? pz : 0.f;
                        Cn += (unsigned)__popcll(b1 & ~ms);
                        Cp += (unsigned)__popcll(__ballot(v1 < 0.19f) & mp);
                    }
                }
            }
        }
    }

    // block reduction: Sn/Sp via shuffles; Cn/Cp already wave-uniform
    #pragma unroll
    for (int off = 32; off >= 1; off >>= 1) {
        Sn += __shfl_down(Sn, off);
        Sp += __shfl_down(Sp, off);
    }
    if (lane == 0) {
        redbuf[wave][0] = Sn; redbuf[wave][1] = (float)Cn;
        redbuf[wave][2] = Sp; redbuf[wave][3] = (float)Cp;
    }
    __syncthreads();
    if (tid < 4) {
        partials[blockIdx.x * 4 + tid] =
            redbuf[0][tid] + redbuf[1][tid] + redbuf[2][tid] + redbuf[3][tid];
    }
}

// Kernel 3: reduce per-block partials + per-row reg terms, emit scalar loss.
// Guard: if a count sums to exactly 0, the true masked sum is 0 too
// (reference yields 0/1e-12 = 0) -> emit 0 instead of residual/1e-12.
__global__ __launch_bounds__(256) void finalize_kernel(
    const float* __restrict__ partials, const float* __restrict__ rabs,
    float* __restrict__ out)
{
    int tid = threadIdx.x;
    float s0 = 0, s1 = 0, s2 = 0, s3 = 0, rr = 0;
    for (int i = tid; i < NBT; i += 256) {
        float4 p = reinterpret_cast<const float4*>(partials)[i];
        s0 += p.x; s1 += p.y; s2 += p.z; s3 += p.w;
    }
    for (int i = tid; i < NROWS; i += 256) rr += rabs[i];

    #pragma unroll
    for (int off = 32; off >= 1; off >>= 1) {
        s0 += __shfl_down(s0, off);
        s1 += __shfl_down(s1, off);
        s2 += __shfl_down(s2, off);
        s3 += __shfl_down(s3, off);
        rr += __shfl_down(rr, off);
    }
    __shared__ float red[4][5];
    int wave = tid >> 6, lane = tid & 63;
    if (lane == 0) {
        red[wave][0] = s0; red[wave][1] = s1; red[wave][2] = s2;
        red[wave][3] = s3; red[wave][4] = rr;
    }
    __syncthreads();
    if (tid == 0) {
        float a0 = 0, a1 = 0, a2 = 0, a3 = 0, a4 = 0;
        #pragma unroll
        for (int w = 0; w < 4; ++w) {
            a0 += red[w][0]; a1 += red[w][1]; a2 += red[w][2];
            a3 += red[w][3]; a4 += red[w][4];
        }
        float neg = (a1 > 0.5f) ? a0 / (a1 + 1e-12f) : 0.0f;
        float pos = (a3 > 0.5f) ? a2 / (a3 + 1e-12f) : 0.0f;
        out[0] = pos + neg + a4 * (0.1f / (float)NROWS);
    }
}

extern "C" void kernel_launch(void* const* d_in, const int* in_sizes, int n_in,
                              void* d_out, int out_size, void* d_ws, size_t ws_size,
                              hipStream_t stream) {
    const float* embeds = (const float*)d_in[0];
    const int*   labels = (const int*)d_in[1];
    float* out = (float*)d_out;

    char* ws = (char*)d_ws;
    unsigned short* ebf = (unsigned short*)ws;              // 4 MB
    float* aP   = (float*)(ws + (size_t)NROWS * DDIM * 2);
    float* bs   = aP + NROWS;
    float* rabs = bs + NROWS;
    float* partials = rabs + NROWS;                         // NBT*4 floats

    rowstats_kernel<<<NROWS / 4, 256, 0, stream>>>(embeds, ebf, aP, bs, rabs);

    snr_gemm_kernel<<<NBT, 256, 0, stream>>>(ebf, aP, bs, labels, partials);

    finalize_kernel<<<1, 256, 0, stream>>>(partials, rabs, out);
}